// Round 1
// baseline (2807.688 us; speedup 1.0000x reference)
//
#include <hip/hip_runtime.h>

#define BATCH 128
#define NAT   128
#define DIM   128
#define CDIM  15
#define CP    17        // padded code dim (zero border)
#define MAXIT 20
#define STEP  0.2f      // 2 * R_LR
#define LMD   0.005f

// workspace layout (floats)
#define SZ_RPAD  (BATCH*CP*CP*NAT)      // 4,734,976
#define SZ_RESID (BATCH*DIM*DIM)        // 2,097,152
#define OFF_RPAD  0
#define OFF_RESID (OFF_RPAD + SZ_RPAD)
#define OFF_WT    (OFF_RESID + SZ_RESID)
#define OFF_W2    (OFF_WT + 256*128)
#define OFF_PART  (OFF_W2 + 512*64)
#define OFF_FLAGS (OFF_PART + 2048)     // ints live here

__global__ void kzero(float* __restrict__ rpad, int* __restrict__ flags) {
    int i = blockIdx.x * 256 + threadIdx.x;
    ((float4*)rpad)[i] = float4{0.f, 0.f, 0.f, 0.f};
    if (blockIdx.x == 0 && threadIdx.x < 32) flags[threadIdx.x] = 0;
}

// Build Wt[kxy][n] (for grad GEMM) and W2[(ij,n)][uv] (for conv_t GEMM)
__global__ void kprep(const float* __restrict__ W, float* __restrict__ Wt,
                      float* __restrict__ W2) {
    int tid = blockIdx.x * 256 + threadIdx.x;   // 32768 = 128 atoms * 256
    int n = tid >> 8, kk = tid & 255;
    float w = W[tid];
    Wt[kk * 128 + n] = w;
    int kx = kk >> 4, ky = kk & 15;
    int u = kx & 7, i = kx >> 3, v = ky & 7, j = ky >> 3;
    W2[((i * 2 + j) * 128 + n) * 64 + u * 8 + v] = w;
}

// conv_t(R) as GEMM. t>=0: outp = img - conv_t(R) (resid), gated on flags[t].
// t<0: outp = conv_t(R) (final reconstruction), ungated.
__global__ __launch_bounds__(256) void kconvt(
    const float* __restrict__ rpad, const float* __restrict__ W2,
    const float* __restrict__ img, float* __restrict__ outp,
    const int* __restrict__ flags, int t) {
    if (t >= 0 && flags[t]) return;
    __shared__ __align__(16) float As[64 * 68];
    __shared__ __align__(16) float Bs[64 * 68];
    const int tid = threadIdx.x;
    const int m0 = blockIdx.x * 64;
    const int tm = tid >> 4, tn = tid & 15;
    float acc[4][4] = {};

    for (int kc = 0; kc < 8; ++kc) {
        const int ijc = kc >> 1;          // (i,j) combo for this K-chunk
        const int ic = ijc >> 1, jc = ijc & 1;
        const int nb = (kc & 1) * 64;     // atom base
#pragma unroll
        for (int tI = 0; tI < 16; ++tI) {
            int idx = tI * 256 + tid;
            // LHS: ml = idx>>6 (cell), kl = idx&63 (atom offset) -> coalesced over n
            int ml = idx >> 6, kl = idx & 63;
            int m = m0 + ml;
            int b = m >> 8, cell = m & 255, px0 = cell >> 4, py0 = cell & 15;
            int row = px0 + 1 - ic, col = py0 + 1 - jc;
            As[kl * 68 + ml] = rpad[((b * CP + row) * CP + col) * NAT + nb + kl];
            // RHS: kl2 = idx>>6 (k), uv = idx&63 -> coalesced over uv
            int kl2 = idx >> 6, uv = idx & 63;
            Bs[kl2 * 68 + uv] = W2[(kc * 64 + kl2) * 64 + uv];
        }
        __syncthreads();
#pragma unroll 8
        for (int k = 0; k < 64; ++k) {
            const float4 a = *(const float4*)&As[k * 68 + tm * 4];
            const float4 bb = *(const float4*)&Bs[k * 68 + tn * 4];
            float av[4] = {a.x, a.y, a.z, a.w};
            float bv[4] = {bb.x, bb.y, bb.z, bb.w};
#pragma unroll
            for (int q = 0; q < 4; ++q)
#pragma unroll
                for (int r = 0; r < 4; ++r)
                    acc[q][r] = fmaf(av[q], bv[r], acc[q][r]);
        }
        __syncthreads();
    }

#pragma unroll
    for (int q = 0; q < 4; ++q) {
        int m = m0 + tm * 4 + q;
        int b = m >> 8, cell = m & 255, px0 = cell >> 4, py0 = cell & 15;
#pragma unroll
        for (int r = 0; r < 4; ++r) {
            int uv = tn * 4 + r;
            int x = px0 * 8 + (uv >> 3), y = py0 * 8 + (uv & 7);
            int idx = b * (DIM * DIM) + x * DIM + y;
            if (t >= 0) outp[idx] = img[idx] - acc[q][r];
            else        outp[idx] = acc[q][r];
        }
    }
}

// grad GEMM + SGD step + soft-threshold + in-place R update + norm partials
__global__ __launch_bounds__(256) void kgrad(
    const float* __restrict__ resid, const float* __restrict__ Wt,
    float* __restrict__ rpad, float* __restrict__ partials,
    const int* __restrict__ flags, int t) {
    if (flags[t]) return;
    __shared__ __align__(16) float As[64 * 68];
    __shared__ __align__(16) float Bs[64 * 68];
    __shared__ float red[16];
    const int tid = threadIdx.x;
    const int m0 = blockIdx.x * 64;
    const int n0 = blockIdx.y * 64;
    const int tm = tid >> 4, tn = tid & 15;
    float acc[4][4] = {};

    for (int kc = 0; kc < 4; ++kc) {
#pragma unroll
        for (int tI = 0; tI < 16; ++tI) {
            int idx = tI * 256 + tid;
            int ml = idx >> 6, kl = idx & 63;
            int m = m0 + ml;
            int b = m / 225, rem = m % 225, px = rem / 15, py = rem % 15;
            int kg = kc * 64 + kl, kx = kg >> 4, ky = kg & 15;
            As[kl * 68 + ml] = resid[b * (DIM * DIM) + (8 * px + kx) * DIM + 8 * py + ky];
            int kl2 = idx >> 6, nl = idx & 63;
            Bs[kl2 * 68 + nl] = Wt[(kc * 64 + kl2) * 128 + n0 + nl];
        }
        __syncthreads();
#pragma unroll 8
        for (int k = 0; k < 64; ++k) {
            const float4 a = *(const float4*)&As[k * 68 + tm * 4];
            const float4 bb = *(const float4*)&Bs[k * 68 + tn * 4];
            float av[4] = {a.x, a.y, a.z, a.w};
            float bv[4] = {bb.x, bb.y, bb.z, bb.w};
#pragma unroll
            for (int q = 0; q < 4; ++q)
#pragma unroll
                for (int r = 0; r < 4; ++r)
                    acc[q][r] = fmaf(av[q], bv[r], acc[q][r]);
        }
        __syncthreads();
    }

    float d2 = 0.f, r2 = 0.f;
#pragma unroll
    for (int q = 0; q < 4; ++q) {
        int m = m0 + tm * 4 + q;
        int b = m / 225, rem = m % 225, px = rem / 15, py = rem % 15;
        float* rp = &rpad[((b * CP + px + 1) * CP + py + 1) * NAT + n0 + tn * 4];
        float4 ro = *(const float4*)rp;
        float rold[4] = {ro.x, ro.y, ro.z, ro.w};
        float rn[4];
#pragma unroll
        for (int r = 0; r < 4; ++r) {
            float v = fmaf(STEP, acc[q][r], rold[r]);
            float st = fmaxf(v - LMD, 0.f) - fmaxf(-v - LMD, 0.f);
            float df = st - rold[r];
            d2 += df * df;
            r2 += rold[r] * rold[r];
            rn[r] = st;
        }
        *(float4*)rp = float4{rn[0], rn[1], rn[2], rn[3]};
    }
    // deterministic block reduction -> per-block partials (summed in kconvchk)
    for (int off = 32; off; off >>= 1) {
        d2 += __shfl_down(d2, off, 64);
        r2 += __shfl_down(r2, off, 64);
    }
    int w = tid >> 6, l = tid & 63;
    if (l == 0) { red[w] = d2; red[8 + w] = r2; }
    __syncthreads();
    if (tid == 0) {
        float td = red[0] + red[1] + red[2] + red[3];
        float tr = red[8] + red[9] + red[10] + red[11];
        int pb = blockIdx.y * 450 + blockIdx.x;
        partials[pb] = td;
        partials[1024 + pb] = tr;
    }
}

__global__ void kconvchk(const float* __restrict__ partials,
                         int* __restrict__ flags, int t) {
    const int tid = threadIdx.x;
    float d2 = 0.f, r2 = 0.f;
    for (int i = tid; i < 900; i += 256) {
        d2 += partials[i];
        r2 += partials[1024 + i];
    }
    for (int off = 32; off; off >>= 1) {
        d2 += __shfl_down(d2, off, 64);
        r2 += __shfl_down(r2, off, 64);
    }
    __shared__ float red[16];
    int w = tid >> 6, l = tid & 63;
    if (l == 0) { red[w] = d2; red[8 + w] = r2; }
    __syncthreads();
    if (tid == 0) {
        float td = red[0] + red[1] + red[2] + red[3];
        float tr = red[8] + red[9] + red[10] + red[11];
        // norm(Rn-R)/norm(R) < 0.01  <=>  d2 < 1e-4*r2  (r2=0 -> false, matches inf/NaN)
        flags[t + 1] = flags[t] | ((td < 1e-4f * tr) ? 1 : 0);
    }
}

extern "C" void kernel_launch(void* const* d_in, const int* in_sizes, int n_in,
                              void* d_out, int out_size, void* d_ws, size_t ws_size,
                              hipStream_t stream) {
    const float* img = (const float*)d_in[0];
    const float* W   = (const float*)d_in[1];
    float* ws       = (float*)d_ws;
    float* rpad     = ws + OFF_RPAD;
    float* resid    = ws + OFF_RESID;
    float* Wt       = ws + OFF_WT;
    float* W2       = ws + OFF_W2;
    float* partials = ws + OFF_PART;
    int*   flags    = (int*)(ws + OFF_FLAGS);
    float* outp     = (float*)d_out;

    kzero<<<SZ_RPAD / 4 / 256, 256, 0, stream>>>(rpad, flags);
    kprep<<<128, 256, 0, stream>>>(W, Wt, W2);
    for (int t = 0; t < MAXIT; ++t) {
        kconvt<<<512, 256, 0, stream>>>(rpad, W2, img, resid, flags, t);
        kgrad<<<dim3(450, 2), 256, 0, stream>>>(resid, Wt, rpad, partials, flags, t);
        kconvchk<<<1, 256, 0, stream>>>(partials, flags, t);
    }
    kconvt<<<512, 256, 0, stream>>>(rpad, W2, img, outp, flags, -1);
}

// Round 3
// 2672.244 us; speedup vs baseline: 1.0507x; 1.0507x over previous
//
#include <hip/hip_runtime.h>

#define BATCH 128
#define NAT   128
#define DIM   128
#define CDIM  15
#define CP    17        // padded code dim (zero border)
#define MAXIT 20
#define STEP  0.2f      // 2 * R_LR
#define LMD   0.005f

// workspace layout (floats)
#define SZ_RPAD  (BATCH*CP*CP*NAT)      // 4,734,976
#define SZ_RESID (BATCH*DIM*DIM)        // 2,097,152
#define OFF_RPAD  0
#define OFF_RESID (OFF_RPAD + SZ_RPAD)
#define OFF_WT    (OFF_RESID + SZ_RESID)
#define OFF_W2    (OFF_WT + 256*128)
#define OFF_PART  (OFF_W2 + 512*64)
#define OFF_FLAGS (OFF_PART + 2048)     // 64 ints: flags[32], counters[32]

#define NGRAD 900   // kgrad block count (450 x 2)

__global__ void kzero(float* __restrict__ rpad, int* __restrict__ flags) {
    int i = blockIdx.x * 256 + threadIdx.x;
    ((float4*)rpad)[i] = float4{0.f, 0.f, 0.f, 0.f};
    if (blockIdx.x == 0 && threadIdx.x < 64) flags[threadIdx.x] = 0;
}

// Build Wt[kxy][n] (for grad GEMM) and W2[(ij*128+n)][uv] (for conv_t GEMM)
__global__ void kprep(const float* __restrict__ W, float* __restrict__ Wt,
                      float* __restrict__ W2) {
    int tid = blockIdx.x * 256 + threadIdx.x;   // 32768 = 128 atoms * 256
    int n = tid >> 8, kk = tid & 255;
    float w = W[tid];
    Wt[kk * 128 + n] = w;
    int kx = kk >> 4, ky = kk & 15;
    int u = kx & 7, i = kx >> 3, v = ky & 7, j = ky >> 3;
    W2[((i * 2 + j) * 128 + n) * 64 + u * 8 + v] = w;
}

// conv_t(R) as GEMM. t>=0: outp = img - conv_t(R) (resid), gated on flags[t].
// t<0: outp = conv_t(R) (final reconstruction), ungated.
__global__ __launch_bounds__(256) void kconvt(
    const float* __restrict__ rpad, const float* __restrict__ W2,
    const float* __restrict__ img, float* __restrict__ outp,
    const int* __restrict__ flags, int t) {
    if (t >= 0 && flags[t]) return;
    __shared__ __align__(16) float As[64 * 68];
    __shared__ __align__(16) float Bs[64 * 68];
    const int tid = threadIdx.x;
    const int m0 = blockIdx.x * 64;
    const int tm = tid >> 4, tn = tid & 15;
    float acc[4][4] = {};
    float4 pa[4], pb[4];

    // prefetch: 4 A-float4 (4 consecutive atoms) + 4 B-float4 per thread
    auto load_chunk = [&](int kc) {
        const int ijc = kc >> 1;
        const int ic = ijc >> 1, jc = ijc & 1;
        const int nb = (kc & 1) * 64;
#pragma unroll
        for (int i = 0; i < 4; ++i) {
            int f = i * 256 + tid;
            int ml = f >> 4, kq = f & 15;   // ml: m-local 0..63, kq: k-quad 0..15
            int m = m0 + ml;
            int b = m >> 8, cell = m & 255, px0 = cell >> 4, py0 = cell & 15;
            int row = px0 + 1 - ic, col = py0 + 1 - jc;
            pa[i] = *(const float4*)&rpad[((b * CP + row) * CP + col) * NAT + nb + kq * 4];
            // B: row ml = k-index 0..63, kq*4 = uv offset
            pb[i] = *(const float4*)&W2[(kc * 64 + ml) * 64 + kq * 4];
        }
    };
    auto write_chunk = [&]() {
#pragma unroll
        for (int i = 0; i < 4; ++i) {
            int f = i * 256 + tid;
            int ml = f >> 4, kq = f & 15;
            // A[m=ml][k=kq*4+c] -> row k, swizzled col quad = (ml>>2)^kq
            int colb = (((ml >> 2) ^ kq) & 15) * 4 + (ml & 3);
            float4 v = pa[i];
            As[(kq * 4 + 0) * 68 + colb] = v.x;
            As[(kq * 4 + 1) * 68 + colb] = v.y;
            As[(kq * 4 + 2) * 68 + colb] = v.z;
            As[(kq * 4 + 3) * 68 + colb] = v.w;
            // B[k=ml][uv=kq*4..+3] -> row ml, col kq*4
            *(float4*)&Bs[ml * 68 + kq * 4] = pb[i];
        }
    };

    load_chunk(0);
    write_chunk();
    __syncthreads();
    for (int kc = 0;; ++kc) {
        if (kc < 7) load_chunk(kc + 1);
#pragma unroll
        for (int kq2 = 0; kq2 < 16; ++kq2) {
            const int acol = ((tm ^ kq2) & 15) * 4;
#pragma unroll
            for (int j4 = 0; j4 < 4; ++j4) {
                const int k = kq2 * 4 + j4;
                const float4 a = *(const float4*)&As[k * 68 + acol];
                const float4 bb = *(const float4*)&Bs[k * 68 + tn * 4];
                float av[4] = {a.x, a.y, a.z, a.w};
                float bv[4] = {bb.x, bb.y, bb.z, bb.w};
#pragma unroll
                for (int q = 0; q < 4; ++q)
#pragma unroll
                    for (int r = 0; r < 4; ++r)
                        acc[q][r] = fmaf(av[q], bv[r], acc[q][r]);
            }
        }
        if (kc == 7) break;
        __syncthreads();
        write_chunk();
        __syncthreads();
    }

    // epilogue: acc[q][0..3] is 4 contiguous y -> one float4 store per q
#pragma unroll
    for (int q = 0; q < 4; ++q) {
        int m = m0 + tm * 4 + q;
        int b = m >> 8, cell = m & 255, px0 = cell >> 4, py0 = cell & 15;
        int x = px0 * 8 + (tn >> 1);
        int y = py0 * 8 + 4 * (tn & 1);
        int idx = b * (DIM * DIM) + x * DIM + y;
        float4 v{acc[q][0], acc[q][1], acc[q][2], acc[q][3]};
        if (t >= 0) {
            float4 im = *(const float4*)&img[idx];
            v = float4{im.x - v.x, im.y - v.y, im.z - v.z, im.w - v.w};
        }
        *(float4*)&outp[idx] = v;
    }
}

// grad GEMM + SGD step + soft-threshold + in-place R update + norm partials
// + fused convergence check (last-arriving block reduces, deterministic order)
__global__ __launch_bounds__(256) void kgrad(
    const float* __restrict__ resid, const float* __restrict__ Wt,
    float* __restrict__ rpad, float* __restrict__ partials,
    int* __restrict__ flags, int* __restrict__ counters, int t) {
    __shared__ __align__(16) float As[64 * 68];
    __shared__ __align__(16) float Bs[64 * 68];
    __shared__ float red[16];
    __shared__ int isred;
    const int tid = threadIdx.x;
    const bool conv = (flags[t] != 0);

    if (!conv) {
        const int m0 = blockIdx.x * 64;
        const int n0 = blockIdx.y * 64;
        const int tm = tid >> 4, tn = tid & 15;
        float acc[4][4] = {};
        float4 pa[4], pb[4];

        auto load_chunk = [&](int kc) {
#pragma unroll
            for (int i = 0; i < 4; ++i) {
                int f = i * 256 + tid;
                int ml = f >> 4, kq = f & 15;
                int m = m0 + ml;
                int b = m / 225, rem = m % 225, px = rem / 15, py = rem % 15;
                int x = 8 * px + kc * 4 + (kq >> 2);
                int y = 8 * py + 4 * (kq & 3);
                pa[i] = *(const float4*)&resid[b * (DIM * DIM) + x * DIM + y];
                pb[i] = *(const float4*)&Wt[(kc * 64 + ml) * 128 + n0 + kq * 4];
            }
        };
        auto write_chunk = [&]() {
#pragma unroll
            for (int i = 0; i < 4; ++i) {
                int f = i * 256 + tid;
                int ml = f >> 4, kq = f & 15;
                int colb = (((ml >> 2) ^ kq) & 15) * 4 + (ml & 3);
                float4 v = pa[i];
                As[(kq * 4 + 0) * 68 + colb] = v.x;
                As[(kq * 4 + 1) * 68 + colb] = v.y;
                As[(kq * 4 + 2) * 68 + colb] = v.z;
                As[(kq * 4 + 3) * 68 + colb] = v.w;
                *(float4*)&Bs[ml * 68 + kq * 4] = pb[i];
            }
        };

        load_chunk(0);
        write_chunk();
        __syncthreads();
        for (int kc = 0;; ++kc) {
            if (kc < 3) load_chunk(kc + 1);
#pragma unroll
            for (int kq2 = 0; kq2 < 16; ++kq2) {
                const int acol = ((tm ^ kq2) & 15) * 4;
#pragma unroll
                for (int j4 = 0; j4 < 4; ++j4) {
                    const int k = kq2 * 4 + j4;
                    const float4 a = *(const float4*)&As[k * 68 + acol];
                    const float4 bb = *(const float4*)&Bs[k * 68 + tn * 4];
                    float av[4] = {a.x, a.y, a.z, a.w};
                    float bv[4] = {bb.x, bb.y, bb.z, bb.w};
#pragma unroll
                    for (int q = 0; q < 4; ++q)
#pragma unroll
                        for (int r = 0; r < 4; ++r)
                            acc[q][r] = fmaf(av[q], bv[r], acc[q][r]);
                }
            }
            if (kc == 3) break;
            __syncthreads();
            write_chunk();
            __syncthreads();
        }

        float d2 = 0.f, r2 = 0.f;
#pragma unroll
        for (int q = 0; q < 4; ++q) {
            int m = m0 + tm * 4 + q;
            int b = m / 225, rem = m % 225, px = rem / 15, py = rem % 15;
            float* rp = &rpad[((b * CP + px + 1) * CP + py + 1) * NAT + n0 + tn * 4];
            float4 ro = *(const float4*)rp;
            float rold[4] = {ro.x, ro.y, ro.z, ro.w};
            float rn[4];
#pragma unroll
            for (int r = 0; r < 4; ++r) {
                float v = fmaf(STEP, acc[q][r], rold[r]);
                float st = fmaxf(v - LMD, 0.f) - fmaxf(-v - LMD, 0.f);
                float df = st - rold[r];
                d2 += df * df;
                r2 += rold[r] * rold[r];
                rn[r] = st;
            }
            *(float4*)rp = float4{rn[0], rn[1], rn[2], rn[3]};
        }
        // deterministic block reduction -> per-block partials
        for (int off = 32; off; off >>= 1) {
            d2 += __shfl_down(d2, off, 64);
            r2 += __shfl_down(r2, off, 64);
        }
        int w = tid >> 6, l = tid & 63;
        if (l == 0) { red[w] = d2; red[8 + w] = r2; }
        __syncthreads();
        if (tid == 0) {
            float td = red[0] + red[1] + red[2] + red[3];
            float tr = red[8] + red[9] + red[10] + red[11];
            int pb2 = blockIdx.y * 450 + blockIdx.x;
            __hip_atomic_store(&partials[pb2], td, __ATOMIC_RELAXED, __HIP_MEMORY_SCOPE_AGENT);
            __hip_atomic_store(&partials[1024 + pb2], tr, __ATOMIC_RELAXED, __HIP_MEMORY_SCOPE_AGENT);
        }
    }

    // ticket: last-arriving block performs the convergence reduction
    if (tid == 0) {
        __threadfence();
        int old = __hip_atomic_fetch_add(&counters[t], 1, __ATOMIC_ACQ_REL, __HIP_MEMORY_SCOPE_AGENT);
        isred = (old == NGRAD - 1) ? 1 : 0;
    }
    __syncthreads();
    if (isred) {
        int res = 1;
        if (!conv) {
            float d2 = 0.f, r2 = 0.f;
            for (int i = tid; i < NGRAD; i += 256) {
                d2 += __hip_atomic_load(&partials[i], __ATOMIC_RELAXED, __HIP_MEMORY_SCOPE_AGENT);
                r2 += __hip_atomic_load(&partials[1024 + i], __ATOMIC_RELAXED, __HIP_MEMORY_SCOPE_AGENT);
            }
            for (int off = 32; off; off >>= 1) {
                d2 += __shfl_down(d2, off, 64);
                r2 += __shfl_down(r2, off, 64);
            }
            int w = tid >> 6, l = tid & 63;
            __syncthreads();
            if (l == 0) { red[w] = d2; red[8 + w] = r2; }
            __syncthreads();
            if (tid == 0) {
                float td = red[0] + red[1] + red[2] + red[3];
                float tr = red[8] + red[9] + red[10] + red[11];
                res = (td < 1e-4f * tr) ? 1 : 0;
            }
        }
        if (tid == 0) flags[t + 1] = (conv || res) ? 1 : 0;
    }
}

extern "C" void kernel_launch(void* const* d_in, const int* in_sizes, int n_in,
                              void* d_out, int out_size, void* d_ws, size_t ws_size,
                              hipStream_t stream) {
    const float* img = (const float*)d_in[0];
    const float* W   = (const float*)d_in[1];
    float* ws       = (float*)d_ws;
    float* rpad     = ws + OFF_RPAD;
    float* resid    = ws + OFF_RESID;
    float* Wt       = ws + OFF_WT;
    float* W2       = ws + OFF_W2;
    float* partials = ws + OFF_PART;
    int*   flags    = (int*)(ws + OFF_FLAGS);
    int*   counters = flags + 32;
    float* outp     = (float*)d_out;

    kzero<<<SZ_RPAD / 4 / 256, 256, 0, stream>>>(rpad, flags);
    kprep<<<128, 256, 0, stream>>>(W, Wt, W2);
    for (int t = 0; t < MAXIT; ++t) {
        kconvt<<<512, 256, 0, stream>>>(rpad, W2, img, resid, flags, t);
        kgrad<<<dim3(450, 2), 256, 0, stream>>>(resid, Wt, rpad, partials, flags, counters, t);
    }
    kconvt<<<512, 256, 0, stream>>>(rpad, W2, img, outp, flags, -1);
}

// Round 4
// 1803.707 us; speedup vs baseline: 1.5566x; 1.4815x over previous
//
#include <hip/hip_runtime.h>

#define BATCH 128
#define NAT   128
#define DIM   128
#define CDIM  15
#define CP    17        // padded code dim (zero border)
#define MAXIT 20
#define STEP  0.2f      // 2 * R_LR
#define LMD   0.005f

// workspace layout (floats)
#define SZ_RPAD  (BATCH*CP*CP*NAT)      // 4,734,976
#define SZ_RESID (BATCH*DIM*DIM)        // 2,097,152
#define OFF_RPAD  0
#define OFF_RESID (OFF_RPAD + SZ_RPAD)
#define OFF_WT    (OFF_RESID + SZ_RESID)
#define OFF_W2    (OFF_WT + 256*128)
#define OFF_PART  (OFF_W2 + 512*64)
#define OFF_FLAGS (OFF_PART + 2048)     // 32 ints: flags

#define NGRAD 900   // kgrad block count (450 x 2)

__global__ void kzero(float* __restrict__ rpad, int* __restrict__ flags) {
    int i = blockIdx.x * 256 + threadIdx.x;
    ((float4*)rpad)[i] = float4{0.f, 0.f, 0.f, 0.f};
    if (blockIdx.x == 0 && threadIdx.x < 32) flags[threadIdx.x] = 0;
}

// Build Wt[kxy][n] (for grad GEMM) and W2[(ij*128+n)][uv] (for conv_t GEMM)
__global__ void kprep(const float* __restrict__ W, float* __restrict__ Wt,
                      float* __restrict__ W2) {
    int tid = blockIdx.x * 256 + threadIdx.x;   // 32768 = 128 atoms * 256
    int n = tid >> 8, kk = tid & 255;
    float w = W[tid];
    Wt[kk * 128 + n] = w;
    int kx = kk >> 4, ky = kk & 15;
    int u = kx & 7, i = kx >> 3, v = ky & 7, j = ky >> 3;
    W2[((i * 2 + j) * 128 + n) * 64 + u * 8 + v] = w;
}

// conv_t(R) as GEMM. t>=1: first computes flags[t] = flags[t-1] | conv(partials)
// (each block locally, block 0 persists it), then skips if converged.
// t<0: final reconstruction, ungated.
__global__ __launch_bounds__(256) void kconvt(
    const float* __restrict__ rpad, const float* __restrict__ W2,
    const float* __restrict__ img, float* __restrict__ outp,
    const float* __restrict__ partials, int* __restrict__ flags, int t) {
    const int tid = threadIdx.x;

    if (t >= 1) {   // convergence gate from previous kgrad's partials
        __shared__ float red[16];
        __shared__ int sgate;
        float d2 = 0.f, r2 = 0.f;
        for (int i = tid; i < NGRAD; i += 256) {
            d2 += partials[i];
            r2 += partials[1024 + i];
        }
        for (int off = 32; off; off >>= 1) {
            d2 += __shfl_down(d2, off, 64);
            r2 += __shfl_down(r2, off, 64);
        }
        int w = tid >> 6, l = tid & 63;
        if (l == 0) { red[w] = d2; red[8 + w] = r2; }
        __syncthreads();
        if (tid == 0) {
            float td = red[0] + red[1] + red[2] + red[3];
            float tr = red[8] + red[9] + red[10] + red[11];
            // norm(Rn-R)/norm(R) < 0.01  <=>  d2 < 1e-4*r2 (r2=0 -> false)
            sgate = flags[t - 1] | ((td < 1e-4f * tr) ? 1 : 0);
            if (blockIdx.x == 0) flags[t] = sgate;   // for kgrad(t)
        }
        __syncthreads();
        if (sgate) return;
    }

    __shared__ __align__(16) float As[64 * 68];
    __shared__ __align__(16) float Bs[64 * 68];
    const int m0 = blockIdx.x * 64;
    const int tm = tid >> 4, tn = tid & 15;
    float acc[4][4] = {};
    float4 pa[4], pb[4];

    // prefetch: 4 A-float4 (4 consecutive atoms) + 4 B-float4 per thread
    auto load_chunk = [&](int kc) {
        const int ijc = kc >> 1;
        const int ic = ijc >> 1, jc = ijc & 1;
        const int nb = (kc & 1) * 64;
#pragma unroll
        for (int i = 0; i < 4; ++i) {
            int f = i * 256 + tid;
            int ml = f >> 4, kq = f & 15;   // ml: m-local 0..63, kq: k-quad 0..15
            int m = m0 + ml;
            int b = m >> 8, cell = m & 255, px0 = cell >> 4, py0 = cell & 15;
            int row = px0 + 1 - ic, col = py0 + 1 - jc;
            pa[i] = *(const float4*)&rpad[((b * CP + row) * CP + col) * NAT + nb + kq * 4];
            pb[i] = *(const float4*)&W2[(kc * 64 + ml) * 64 + kq * 4];
        }
    };
    auto write_chunk = [&]() {
#pragma unroll
        for (int i = 0; i < 4; ++i) {
            int f = i * 256 + tid;
            int ml = f >> 4, kq = f & 15;
            int colb = (((ml >> 2) ^ kq) & 15) * 4 + (ml & 3);
            float4 v = pa[i];
            As[(kq * 4 + 0) * 68 + colb] = v.x;
            As[(kq * 4 + 1) * 68 + colb] = v.y;
            As[(kq * 4 + 2) * 68 + colb] = v.z;
            As[(kq * 4 + 3) * 68 + colb] = v.w;
            *(float4*)&Bs[ml * 68 + kq * 4] = pb[i];
        }
    };

    load_chunk(0);
    write_chunk();
    __syncthreads();
    for (int kc = 0;; ++kc) {
        if (kc < 7) load_chunk(kc + 1);
#pragma unroll
        for (int kq2 = 0; kq2 < 16; ++kq2) {
            const int acol = ((tm ^ kq2) & 15) * 4;
#pragma unroll
            for (int j4 = 0; j4 < 4; ++j4) {
                const int k = kq2 * 4 + j4;
                const float4 a = *(const float4*)&As[k * 68 + acol];
                const float4 bb = *(const float4*)&Bs[k * 68 + tn * 4];
                float av[4] = {a.x, a.y, a.z, a.w};
                float bv[4] = {bb.x, bb.y, bb.z, bb.w};
#pragma unroll
                for (int q = 0; q < 4; ++q)
#pragma unroll
                    for (int r = 0; r < 4; ++r)
                        acc[q][r] = fmaf(av[q], bv[r], acc[q][r]);
            }
        }
        if (kc == 7) break;
        __syncthreads();
        write_chunk();
        __syncthreads();
    }

    // epilogue: acc[q][0..3] is 4 contiguous y -> one float4 store per q
#pragma unroll
    for (int q = 0; q < 4; ++q) {
        int m = m0 + tm * 4 + q;
        int b = m >> 8, cell = m & 255, px0 = cell >> 4, py0 = cell & 15;
        int x = px0 * 8 + (tn >> 1);
        int y = py0 * 8 + 4 * (tn & 1);
        int idx = b * (DIM * DIM) + x * DIM + y;
        float4 v{acc[q][0], acc[q][1], acc[q][2], acc[q][3]};
        if (t >= 0) {
            float4 im = *(const float4*)&img[idx];
            v = float4{im.x - v.x, im.y - v.y, im.z - v.z, im.w - v.w};
        }
        *(float4*)&outp[idx] = v;
    }
}

// grad GEMM + SGD step + soft-threshold + in-place R update + norm partials.
// No atomics/fences: partials are plain stores, consumed by the NEXT dispatch.
__global__ __launch_bounds__(256) void kgrad(
    const float* __restrict__ resid, const float* __restrict__ Wt,
    float* __restrict__ rpad, float* __restrict__ partials,
    const int* __restrict__ flags, int t) {
    if (flags[t]) return;
    __shared__ __align__(16) float As[64 * 68];
    __shared__ __align__(16) float Bs[64 * 68];
    __shared__ float red[16];
    const int tid = threadIdx.x;
    const int m0 = blockIdx.x * 64;
    const int n0 = blockIdx.y * 64;
    const int tm = tid >> 4, tn = tid & 15;
    float acc[4][4] = {};
    float4 pa[4], pb[4];

    auto load_chunk = [&](int kc) {
#pragma unroll
        for (int i = 0; i < 4; ++i) {
            int f = i * 256 + tid;
            int ml = f >> 4, kq = f & 15;
            int m = m0 + ml;
            int b = m / 225, rem = m % 225, px = rem / 15, py = rem % 15;
            int x = 8 * px + kc * 4 + (kq >> 2);
            int y = 8 * py + 4 * (kq & 3);
            pa[i] = *(const float4*)&resid[b * (DIM * DIM) + x * DIM + y];
            pb[i] = *(const float4*)&Wt[(kc * 64 + ml) * 128 + n0 + kq * 4];
        }
    };
    auto write_chunk = [&]() {
#pragma unroll
        for (int i = 0; i < 4; ++i) {
            int f = i * 256 + tid;
            int ml = f >> 4, kq = f & 15;
            int colb = (((ml >> 2) ^ kq) & 15) * 4 + (ml & 3);
            float4 v = pa[i];
            As[(kq * 4 + 0) * 68 + colb] = v.x;
            As[(kq * 4 + 1) * 68 + colb] = v.y;
            As[(kq * 4 + 2) * 68 + colb] = v.z;
            As[(kq * 4 + 3) * 68 + colb] = v.w;
            *(float4*)&Bs[ml * 68 + kq * 4] = pb[i];
        }
    };

    load_chunk(0);
    write_chunk();
    __syncthreads();
    for (int kc = 0;; ++kc) {
        if (kc < 3) load_chunk(kc + 1);
#pragma unroll
        for (int kq2 = 0; kq2 < 16; ++kq2) {
            const int acol = ((tm ^ kq2) & 15) * 4;
#pragma unroll
            for (int j4 = 0; j4 < 4; ++j4) {
                const int k = kq2 * 4 + j4;
                const float4 a = *(const float4*)&As[k * 68 + acol];
                const float4 bb = *(const float4*)&Bs[k * 68 + tn * 4];
                float av[4] = {a.x, a.y, a.z, a.w};
                float bv[4] = {bb.x, bb.y, bb.z, bb.w};
#pragma unroll
                for (int q = 0; q < 4; ++q)
#pragma unroll
                    for (int r = 0; r < 4; ++r)
                        acc[q][r] = fmaf(av[q], bv[r], acc[q][r]);
            }
        }
        if (kc == 3) break;
        __syncthreads();
        write_chunk();
        __syncthreads();
    }

    float d2 = 0.f, r2 = 0.f;
#pragma unroll
    for (int q = 0; q < 4; ++q) {
        int m = m0 + tm * 4 + q;
        int b = m / 225, rem = m % 225, px = rem / 15, py = rem % 15;
        float* rp = &rpad[((b * CP + px + 1) * CP + py + 1) * NAT + n0 + tn * 4];
        float4 ro = *(const float4*)rp;
        float rold[4] = {ro.x, ro.y, ro.z, ro.w};
        float rn[4];
#pragma unroll
        for (int r = 0; r < 4; ++r) {
            float v = fmaf(STEP, acc[q][r], rold[r]);
            float st = fmaxf(v - LMD, 0.f) - fmaxf(-v - LMD, 0.f);
            float df = st - rold[r];
            d2 += df * df;
            r2 += rold[r] * rold[r];
            rn[r] = st;
        }
        *(float4*)rp = float4{rn[0], rn[1], rn[2], rn[3]};
    }
    // deterministic block reduction -> per-block partials (plain stores)
    for (int off = 32; off; off >>= 1) {
        d2 += __shfl_down(d2, off, 64);
        r2 += __shfl_down(r2, off, 64);
    }
    int w = tid >> 6, l = tid & 63;
    if (l == 0) { red[w] = d2; red[8 + w] = r2; }
    __syncthreads();
    if (tid == 0) {
        float td = red[0] + red[1] + red[2] + red[3];
        float tr = red[8] + red[9] + red[10] + red[11];
        int pb2 = blockIdx.y * 450 + blockIdx.x;
        partials[pb2] = td;
        partials[1024 + pb2] = tr;
    }
}

extern "C" void kernel_launch(void* const* d_in, const int* in_sizes, int n_in,
                              void* d_out, int out_size, void* d_ws, size_t ws_size,
                              hipStream_t stream) {
    const float* img = (const float*)d_in[0];
    const float* W   = (const float*)d_in[1];
    float* ws       = (float*)d_ws;
    float* rpad     = ws + OFF_RPAD;
    float* resid    = ws + OFF_RESID;
    float* Wt       = ws + OFF_WT;
    float* W2       = ws + OFF_W2;
    float* partials = ws + OFF_PART;
    int*   flags    = (int*)(ws + OFF_FLAGS);
    float* outp     = (float*)d_out;

    kzero<<<SZ_RPAD / 4 / 256, 256, 0, stream>>>(rpad, flags);
    kprep<<<128, 256, 0, stream>>>(W, Wt, W2);
    for (int t = 0; t < MAXIT; ++t) {
        kconvt<<<512, 256, 0, stream>>>(rpad, W2, img, resid, partials, flags, t);
        kgrad<<<dim3(450, 2), 256, 0, stream>>>(resid, Wt, rpad, partials, flags, t);
    }
    kconvt<<<512, 256, 0, stream>>>(rpad, W2, img, outp, partials, flags, -1);
}

// Round 5
// 787.039 us; speedup vs baseline: 3.5674x; 2.2918x over previous
//
#include <hip/hip_runtime.h>
#include <stdint.h>

#define BATCH 128
#define NAT   128
#define DIM   128
#define CP    17
#define MAXIT 20
#define STEP  0.2f      // 2 * R_LR
#define LMD   0.005f
#define NGRAD 900

typedef short bf16x8 __attribute__((ext_vector_type(8)));   // 8 bf16 (4 VGPR)
typedef float f32x16 __attribute__((ext_vector_type(16)));  // 32x32 C/D

#define SZ_RP (BATCH*CP*CP*NAT)     // 4,734,976 elems
#define SZ_RS (BATCH*DIM*DIM)       // 2,097,152 elems
// workspace byte offsets (all 16B-aligned)
#define O_RPH  0
#define O_RPL  (O_RPH + SZ_RP*2)
#define O_RSH  (O_RPL + SZ_RP*2)
#define O_RSL  (O_RSH + SZ_RS*2)
#define O_W2H  (O_RSL + SZ_RS*2)
#define O_W2L  (O_W2H + 64*512*2)
#define O_WTH  (O_W2L + 64*512*2)
#define O_WTL  (O_WTH + 128*256*2)
#define O_PART (O_WTL + 128*256*2)
#define O_FLAG (O_PART + 2048*4)

// split fp32 -> hi/lo bf16 (RNE); hi+lo carries ~16 mantissa bits
__device__ __forceinline__ void split2(float x, ushort& h, ushort& l) {
    uint32_t u = __float_as_uint(x);
    uint32_t hr = (u + 0x7FFFu + ((u >> 16) & 1u)) >> 16;
    h = (ushort)hr;
    float r = x - __uint_as_float(hr << 16);
    uint32_t u2 = __float_as_uint(r);
    l = (ushort)((u2 + 0x7FFFu + ((u2 >> 16) & 1u)) >> 16);
}
__device__ __forceinline__ float us2f(ushort u) {
    return __uint_as_float(((uint32_t)u) << 16);
}

__global__ void kzero(uint4* __restrict__ rp, int* __restrict__ flags) {
    int i = blockIdx.x * 256 + threadIdx.x;
    rp[i] = uint4{0u, 0u, 0u, 0u};   // covers rpad hi+lo planes
    if (blockIdx.x == 0 && threadIdx.x < 32) flags[threadIdx.x] = 0;
}

// WtT = W layout [n][256]; W2T[uv][ij*128+n]; both as hi/lo bf16 planes
__global__ void kprep(const float* __restrict__ W,
                      ushort* __restrict__ wth, ushort* __restrict__ wtl,
                      ushort* __restrict__ w2h, ushort* __restrict__ w2l) {
    int tid = blockIdx.x * 256 + threadIdx.x;   // 32768
    int n = tid >> 8, kk = tid & 255;
    ushort h, l; split2(W[tid], h, l);
    wth[tid] = h; wtl[tid] = l;
    int kx = kk >> 4, ky = kk & 15;
    int uv = (kx & 7) * 8 + (ky & 7);
    int k2 = ((kx >> 3) * 2 + (ky >> 3)) * 128 + n;
    w2h[uv * 512 + k2] = h; w2l[uv * 512 + k2] = l;
}

// conv_t(R) as MFMA GEMM: C[m=cell, uv=64] = Rpad[m,K=512] x W2T^T.
// t>=1: gate from partials first. t>=0: resid = img - C (bf16 hi/lo planes).
// t<0: final fp32 reconstruction to outp.
__global__ __launch_bounds__(256) void kconvt(
    const ushort* __restrict__ rph, const ushort* __restrict__ rpl,
    const ushort* __restrict__ w2h, const ushort* __restrict__ w2l,
    const float* __restrict__ img, float* __restrict__ outp,
    ushort* __restrict__ rsh, ushort* __restrict__ rsl,
    const float* __restrict__ partials, int* __restrict__ flags, int t)
{
    const int tid = threadIdx.x;
    if (t >= 1) {   // convergence gate (deterministic, same in every block)
        __shared__ float red0[16];
        __shared__ int sgate;
        float d2 = 0.f, r2 = 0.f;
        for (int i = tid; i < NGRAD; i += 256) { d2 += partials[i]; r2 += partials[1024 + i]; }
        for (int off = 32; off; off >>= 1) { d2 += __shfl_down(d2, off, 64); r2 += __shfl_down(r2, off, 64); }
        int w = tid >> 6, l = tid & 63;
        if (l == 0) { red0[w] = d2; red0[8 + w] = r2; }
        __syncthreads();
        if (tid == 0) {
            float td = red0[0] + red0[1] + red0[2] + red0[3];
            float tr = red0[8] + red0[9] + red0[10] + red0[11];
            sgate = flags[t - 1] | ((td < 1e-4f * tr) ? 1 : 0);
            if (blockIdx.x == 0) flags[t] = sgate;
        }
        __syncthreads();
        if (sgate) return;
    }

    __shared__ uint4 lds[2048];   // Ahi[512] Alo[512] Bhi[512] Blo[512], 16B units
    const int bx = blockIdx.x;
    const int bid = ((bx & 7) << 6) | (bx >> 3);   // XCD swizzle, 512%8==0
    const int m0 = bid * 64;
    const int ml = tid >> 2, q = tid & 3;
    const int lane = tid & 63, wv = tid >> 6, wm = wv >> 1, wn = wv & 1, g = lane >> 5;
    const int mm = m0 + ml;
    const int b_ = mm >> 8, cell = mm & 255, px0 = cell >> 4, py0 = cell & 15;

    uint4 pa0, pa1, pb0, pb1, pc0, pc1, pd0, pd1;
    auto load_chunk = [&](int kc) {
        const int ij = kc >> 1, ic = ij >> 1, jc = ij & 1;
        const int nb = (kc & 1) * 64;
        const int off = ((b_ * CP + px0 + 1 - ic) * CP + py0 + 1 - jc) * NAT + nb + q * 16;
        pa0 = ((const uint4*)(rph + off))[0]; pa1 = ((const uint4*)(rph + off))[1];
        pb0 = ((const uint4*)(rpl + off))[0]; pb1 = ((const uint4*)(rpl + off))[1];
        const int bo = ml * 512 + kc * 64 + q * 16;
        pc0 = ((const uint4*)(w2h + bo))[0]; pc1 = ((const uint4*)(w2h + bo))[1];
        pd0 = ((const uint4*)(w2l + bo))[0]; pd1 = ((const uint4*)(w2l + bo))[1];
    };
    auto write_chunk = [&]() {
        int e0 = (q * 2) ^ (ml & 7), e1 = (q * 2 + 1) ^ (ml & 7);
        lds[       ml * 8 + e0] = pa0; lds[       ml * 8 + e1] = pa1;
        lds[512  + ml * 8 + e0] = pb0; lds[512  + ml * 8 + e1] = pb1;
        lds[1024 + ml * 8 + e0] = pc0; lds[1024 + ml * 8 + e1] = pc1;
        lds[1536 + ml * 8 + e0] = pd0; lds[1536 + ml * 8 + e1] = pd1;
    };

    f32x16 acc = {};
    const int arow = wm * 32 + (lane & 31);   // m-local row
    const int brow = wn * 32 + (lane & 31);   // uv row
    const int ax = lane & 7;                  // = arow&7 = brow&7
    load_chunk(0); write_chunk(); __syncthreads();
    for (int kc = 0;; ++kc) {
        if (kc < 7) load_chunk(kc + 1);
#pragma unroll
        for (int ks = 0; ks < 4; ++ks) {
            int un = (ks * 2 + g) ^ ax;
            bf16x8 Ah = __builtin_bit_cast(bf16x8, lds[       arow * 8 + un]);
            bf16x8 Al = __builtin_bit_cast(bf16x8, lds[512  + arow * 8 + un]);
            bf16x8 Bh = __builtin_bit_cast(bf16x8, lds[1024 + brow * 8 + un]);
            bf16x8 Bl = __builtin_bit_cast(bf16x8, lds[1536 + brow * 8 + un]);
            acc = __builtin_amdgcn_mfma_f32_32x32x16_bf16(Ah, Bh, acc, 0, 0, 0);
            acc = __builtin_amdgcn_mfma_f32_32x32x16_bf16(Ah, Bl, acc, 0, 0, 0);
            acc = __builtin_amdgcn_mfma_f32_32x32x16_bf16(Al, Bh, acc, 0, 0, 0);
        }
        if (kc == 7) break;
        __syncthreads(); write_chunk(); __syncthreads();
    }

    // C/D: col = lane&31 (uv), row = (r&3) + 8*(r>>2) + 4*(lane>>5)
    const int uv = wn * 32 + (lane & 31);
    const int uu = uv >> 3, vv = uv & 7;
#pragma unroll
    for (int r = 0; r < 16; ++r) {
        int mr = m0 + wm * 32 + (r & 3) + 8 * (r >> 2) + 4 * g;
        int bb = mr >> 8, cl = mr & 255;
        int idx = bb * DIM * DIM + ((cl >> 4) * 8 + uu) * DIM + (cl & 15) * 8 + vv;
        float a = acc[r];
        if (t >= 0) {
            float rv = img[idx] - a;
            ushort h, l; split2(rv, h, l);
            rsh[idx] = h; rsl[idx] = l;
        } else {
            outp[idx] = a;
        }
    }
}

// grad MFMA GEMM g[m=cell, n=atom] = residpatch[m,K=256] x WtT^T,
// fused SGD + soft-threshold + R(hi/lo) update + norm partials (plain stores)
__global__ __launch_bounds__(256) void kgrad(
    const ushort* __restrict__ rsh, const ushort* __restrict__ rsl,
    const ushort* __restrict__ wth, const ushort* __restrict__ wtl,
    ushort* __restrict__ rph, ushort* __restrict__ rpl,
    float* __restrict__ partials, const int* __restrict__ flags, int t)
{
    if (flags[t]) return;
    __shared__ uint4 lds[2048];
    __shared__ float red0[16];
    const int tid = threadIdx.x;
    const int bx = blockIdx.x;
    const int xcd = bx & 7;   // bijective XCD swizzle for nwg=450 (q=56,r=2)
    const int bid = (xcd < 2 ? xcd * 57 : 114 + (xcd - 2) * 56) + (bx >> 3);
    const int m0 = bid * 64;
    const int n0 = blockIdx.y * 64;
    const int ml = tid >> 2, q = tid & 3;
    const int lane = tid & 63, wv = tid >> 6, wm = wv >> 1, wn = wv & 1, g = lane >> 5;
    const int mm = m0 + ml;
    const int b_ = mm / 225, rem = mm % 225, px = rem / 15, py = rem % 15;

    uint4 pa0, pa1, pb0, pb1, pc0, pc1, pd0, pd1;
    auto load_chunk = [&](int kc) {
        const int off = b_ * DIM * DIM + (8 * px + kc * 4 + q) * DIM + 8 * py;
        pa0 = ((const uint4*)(rsh + off))[0]; pa1 = ((const uint4*)(rsh + off))[1];
        pb0 = ((const uint4*)(rsl + off))[0]; pb1 = ((const uint4*)(rsl + off))[1];
        const int bo = (n0 + ml) * 256 + kc * 64 + q * 16;
        pc0 = ((const uint4*)(wth + bo))[0]; pc1 = ((const uint4*)(wth + bo))[1];
        pd0 = ((const uint4*)(wtl + bo))[0]; pd1 = ((const uint4*)(wtl + bo))[1];
    };
    auto write_chunk = [&]() {
        int e0 = (q * 2) ^ (ml & 7), e1 = (q * 2 + 1) ^ (ml & 7);
        lds[       ml * 8 + e0] = pa0; lds[       ml * 8 + e1] = pa1;
        lds[512  + ml * 8 + e0] = pb0; lds[512  + ml * 8 + e1] = pb1;
        lds[1024 + ml * 8 + e0] = pc0; lds[1024 + ml * 8 + e1] = pc1;
        lds[1536 + ml * 8 + e0] = pd0; lds[1536 + ml * 8 + e1] = pd1;
    };

    f32x16 acc = {};
    const int arow = wm * 32 + (lane & 31);
    const int brow = wn * 32 + (lane & 31);
    const int ax = lane & 7;
    load_chunk(0); write_chunk(); __syncthreads();
    for (int kc = 0;; ++kc) {
        if (kc < 3) load_chunk(kc + 1);
#pragma unroll
        for (int ks = 0; ks < 4; ++ks) {
            int un = (ks * 2 + g) ^ ax;
            bf16x8 Ah = __builtin_bit_cast(bf16x8, lds[       arow * 8 + un]);
            bf16x8 Al = __builtin_bit_cast(bf16x8, lds[512  + arow * 8 + un]);
            bf16x8 Bh = __builtin_bit_cast(bf16x8, lds[1024 + brow * 8 + un]);
            bf16x8 Bl = __builtin_bit_cast(bf16x8, lds[1536 + brow * 8 + un]);
            acc = __builtin_amdgcn_mfma_f32_32x32x16_bf16(Ah, Bh, acc, 0, 0, 0);
            acc = __builtin_amdgcn_mfma_f32_32x32x16_bf16(Ah, Bl, acc, 0, 0, 0);
            acc = __builtin_amdgcn_mfma_f32_32x32x16_bf16(Al, Bh, acc, 0, 0, 0);
        }
        if (kc == 3) break;
        __syncthreads(); write_chunk(); __syncthreads();
    }

    float d2 = 0.f, r2 = 0.f;
    const int nn = n0 + wn * 32 + (lane & 31);
#pragma unroll
    for (int r = 0; r < 16; ++r) {
        int mr = m0 + wm * 32 + (r & 3) + 8 * (r >> 2) + 4 * g;
        int bb = mr / 225, rm = mr % 225, pxx = rm / 15, pyy = rm % 15;
        int idx = ((bb * CP + pxx + 1) * CP + pyy + 1) * NAT + nn;
        float rold = us2f(rph[idx]) + us2f(rpl[idx]);
        float v = fmaf(STEP, acc[r], rold);      // grad in acc = -0.5*dL/dR scale folded: STEP=2*lr
        float st = fmaxf(v - LMD, 0.f) - fmaxf(-v - LMD, 0.f);
        float df = st - rold;
        d2 += df * df; r2 += rold * rold;
        ushort h, l; split2(st, h, l);
        rph[idx] = h; rpl[idx] = l;
    }
    for (int off = 32; off; off >>= 1) { d2 += __shfl_down(d2, off, 64); r2 += __shfl_down(r2, off, 64); }
    int w = tid >> 6, l = tid & 63;
    if (l == 0) { red0[w] = d2; red0[8 + w] = r2; }
    __syncthreads();
    if (tid == 0) {
        float td = red0[0] + red0[1] + red0[2] + red0[3];
        float tr = red0[8] + red0[9] + red0[10] + red0[11];
        int pb2 = blockIdx.y * 450 + bid;
        partials[pb2] = td;
        partials[1024 + pb2] = tr;
    }
}

extern "C" void kernel_launch(void* const* d_in, const int* in_sizes, int n_in,
                              void* d_out, int out_size, void* d_ws, size_t ws_size,
                              hipStream_t stream) {
    const float* img = (const float*)d_in[0];
    const float* W   = (const float*)d_in[1];
    char* ws = (char*)d_ws;
    ushort* rph = (ushort*)(ws + O_RPH);
    ushort* rpl = (ushort*)(ws + O_RPL);
    ushort* rsh = (ushort*)(ws + O_RSH);
    ushort* rsl = (ushort*)(ws + O_RSL);
    ushort* w2h = (ushort*)(ws + O_W2H);
    ushort* w2l = (ushort*)(ws + O_W2L);
    ushort* wth = (ushort*)(ws + O_WTH);
    ushort* wtl = (ushort*)(ws + O_WTL);
    float* partials = (float*)(ws + O_PART);
    int*   flags    = (int*)(ws + O_FLAG);
    float* outp = (float*)d_out;

    kzero<<<4624, 256, 0, stream>>>((uint4*)(ws + O_RPH), flags);  // rpad hi+lo = 18,939,904 B
    kprep<<<128, 256, 0, stream>>>(W, wth, wtl, w2h, w2l);
    for (int t = 0; t < MAXIT; ++t) {
        kconvt<<<512, 256, 0, stream>>>(rph, rpl, w2h, w2l, img, nullptr, rsh, rsl, partials, flags, t);
        kgrad<<<dim3(450, 2), 256, 0, stream>>>(rsh, rsl, wth, wtl, rph, rpl, partials, flags, t);
    }
    kconvt<<<512, 256, 0, stream>>>(rph, rpl, w2h, w2l, img, outp, rsh, rsl, partials, flags, -1);
}